// Round 2
// baseline (260.132 us; speedup 1.0000x reference)
//
#include <hip/hip_runtime.h>

#define T_IN   1048576
#define T_OUT  1048564              // T_IN - 12 (valid 5-tap then valid 9-tap)
#define QPR    262141               // output float4 quads per row (T_OUT/4)
#define SEGS   4                    // quads per thread (interleaved by 256)
#define BPR    256                  // blocks per row: 256*256*4 = 262144 >= QPR
#define NROWS  32

// v3: interleaved thread-coarsening, no LDS, no barriers.
// Thread t of block b handles quads {1024b + t + 256s : s=0..3}.
// Every global load/store instruction is lane-contiguous (16 B lane stride,
// ~1 KB contiguous span per instruction) -> minimal cache-line transactions.
// Each quad's 16-float input window is fetched as 4 overlapping coalesced
// float4 loads; the 3/4 redundancy is served by L1, HBM traffic stays 1x.
// All 16 loads are issued before any use: 16 KB in flight per wave.
__device__ __forceinline__ void compose13(const float* __restrict__ fd,
                                          const float* __restrict__ gs,
                                          float c[13])
{
    float f[5], g[9];
#pragma unroll
    for (int i = 0; i < 5; ++i) f[i] = fd[i];
#pragma unroll
    for (int j = 0; j < 9; ++j) g[j] = gs[j];
#pragma unroll
    for (int k = 0; k < 13; ++k) c[k] = 0.0f;
#pragma unroll
    for (int i = 0; i < 5; ++i)
#pragma unroll
        for (int j = 0; j < 9; ++j) c[i + j] = fmaf(f[i], g[j], c[i + j]);
}

__global__ __launch_bounds__(256) void pinn_fused_conv13_v3(
    const float* __restrict__ x,
    const float* __restrict__ fd,     // 5 taps (already scaled by 1/h^2)
    const float* __restrict__ gs,     // 9 taps
    float* __restrict__ out)
{
    const int r  = blockIdx.x >> 8;         // row 0..31
    const int b  = blockIdx.x & (BPR - 1);  // block-in-row
    const int t  = threadIdx.x;
    const int q0 = (b << 10) + t;           // quad for segment 0; +256 per segment

    const float* __restrict__ xrow = x + (size_t)r * T_IN;
    float*       __restrict__ orow = out + (size_t)r * T_OUT;

    // ---- issue all loads first (coalesced; 16 KB in flight per wave) ----
    float4 v[SEGS][4];
#pragma unroll
    for (int s = 0; s < SEGS; ++s) {
        const int q = q0 + (s << 8);
        if (q < QPR) {
            // inputs [4q, 4q+16); max = 4*262140+16 = 1048576 = T_IN. safe.
            const float* p = xrow + (q << 2);
#pragma unroll
            for (int i = 0; i < 4; ++i)
                v[s][i] = *reinterpret_cast<const float4*>(p + 4 * i);
        } else {
            // only the last 3 quads of the last block in each row
#pragma unroll
            for (int i = 0; i < 4; ++i)
                v[s][i] = make_float4(0.f, 0.f, 0.f, 0.f);
        }
    }

    // ---- compose 13-tap kernel while loads are in flight ----
    float c[13];
    compose13(fd, gs, c);

    // ---- compute + store per segment ----
#pragma unroll
    for (int s = 0; s < SEGS; ++s) {
        const int q = q0 + (s << 8);
        if (q < QPR) {
            const float a[16] = {
                v[s][0].x, v[s][0].y, v[s][0].z, v[s][0].w,
                v[s][1].x, v[s][1].y, v[s][1].z, v[s][1].w,
                v[s][2].x, v[s][2].y, v[s][2].z, v[s][2].w,
                v[s][3].x, v[s][3].y, v[s][3].z, v[s][3].w};
            float4 ov;
            float* op = &ov.x;
#pragma unroll
            for (int j = 0; j < 4; ++j) {
                float sacc = c[0] * a[j];
#pragma unroll
                for (int k = 1; k < 13; ++k) sacc = fmaf(c[k], a[j + k], sacc);
                op[j] = sacc;
            }
            *reinterpret_cast<float4*>(orow + (q << 2)) = ov;
        }
    }
}

extern "C" void kernel_launch(void* const* d_in, const int* in_sizes, int n_in,
                              void* d_out, int out_size, void* d_ws, size_t ws_size,
                              hipStream_t stream) {
    const float* x  = (const float*)d_in[0];
    const float* fd = (const float*)d_in[1];
    const float* gs = (const float*)d_in[2];
    float* out = (float*)d_out;

    // 32 rows x 256 blocks/row = 8192 blocks of 256 threads, 16 outputs/thread.
    pinn_fused_conv13_v3<<<NROWS * BPR, 256, 0, stream>>>(x, fd, gs, out);
}

// Round 4
// 249.279 us; speedup vs baseline: 1.0435x; 1.0435x over previous
//
#include <hip/hip_runtime.h>

#define T_IN   1048576
#define T_OUT  1048564              // T_IN - 12 (valid 5-tap then valid 9-tap)
#define QPR    262141               // output float4 quads per row
#define NROWS  32
#define BLKROW 64                   // blocks per row (persistent: 2048 blocks total ~ 8/CU)
#define SLOTS  (BLKROW * 256)       // 16384 quad-slots per row
#define NIT    16                   // ceil(QPR / SLOTS)

typedef float v4f __attribute__((ext_vector_type(4)));  // clang-native, OK for nontemporal builtin

// v4b: persistent waves + register double-buffered software pipeline.
// Each thread owns 16 quads at stride SLOTS; iteration i+1's 4 loads are
// issued before iteration i's compute+store, so every wave keeps 4-8
// coalesced loads in flight for its entire lifetime (copy-bench structure).
// Stores are nontemporal: 'out' is never re-read, keep x resident in L3.
__device__ __forceinline__ void compose13(const float* __restrict__ fd,
                                          const float* __restrict__ gs,
                                          float c[13])
{
    float f[5], g[9];
#pragma unroll
    for (int i = 0; i < 5; ++i) f[i] = fd[i];
#pragma unroll
    for (int j = 0; j < 9; ++j) g[j] = gs[j];
#pragma unroll
    for (int k = 0; k < 13; ++k) c[k] = 0.0f;
#pragma unroll
    for (int i = 0; i < 5; ++i)
#pragma unroll
        for (int j = 0; j < 9; ++j) c[i + j] = fmaf(f[i], g[j], c[i + j]);
}

__global__ __launch_bounds__(256) void pinn_fused_conv13_v4(
    const float* __restrict__ x,
    const float* __restrict__ fd,     // 5 taps (already scaled by 1/h^2)
    const float* __restrict__ gs,     // 9 taps
    float* __restrict__ out)
{
    const int r = blockIdx.y;
    const int t = threadIdx.x;
    int q = (blockIdx.x << 8) + t;    // slot in [0, SLOTS); advance by SLOTS

    const float* __restrict__ xrow = x + (size_t)r * T_IN;
    float*       __restrict__ orow = out + (size_t)r * T_OUT;

    float c[13];
    compose13(fd, gs, c);

    v4f A0, A1, A2, A3, B0, B1, B2, B3;

    // inputs [4Q, 4Q+16): max = 4*262140 + 16 = 1048576 = T_IN (end-exclusive, safe)
#define LOADQ(R0, R1, R2, R3, Q) do {                                   \
        if ((Q) < QPR) {                                                \
            const float* _p = xrow + ((size_t)(Q) << 2);                \
            R0 = *reinterpret_cast<const v4f*>(_p);                     \
            R1 = *reinterpret_cast<const v4f*>(_p + 4);                 \
            R2 = *reinterpret_cast<const v4f*>(_p + 8);                 \
            R3 = *reinterpret_cast<const v4f*>(_p + 12);                \
        } } while (0)

#define CSTORE(R0, R1, R2, R3, Q) do {                                  \
        if ((Q) < QPR) {                                                \
            const float a[16] = {R0.x, R0.y, R0.z, R0.w,                \
                                 R1.x, R1.y, R1.z, R1.w,                \
                                 R2.x, R2.y, R2.z, R2.w,                \
                                 R3.x, R3.y, R3.z, R3.w};               \
            v4f ov;                                                     \
            _Pragma("unroll")                                           \
            for (int j = 0; j < 4; ++j) {                               \
                float s = c[0] * a[j];                                  \
                _Pragma("unroll")                                       \
                for (int k = 1; k < 13; ++k) s = fmaf(c[k], a[j+k], s); \
                ov[j] = s;                                              \
            }                                                           \
            __builtin_nontemporal_store(ov,                             \
                reinterpret_cast<v4f*>(orow + ((size_t)(Q) << 2)));     \
        } } while (0)

    // prologue
    LOADQ(A0, A1, A2, A3, q);

    // 8 unrolled pairs = 16 iterations; the final LOADQ targets iteration 16
    // which is always out of range (guard kills it) — harmless.
#pragma unroll 1
    for (int i = 0; i < NIT / 2; ++i) {
        LOADQ (B0, B1, B2, B3, q + SLOTS);      // prefetch next
        CSTORE(A0, A1, A2, A3, q);              // compute current
        LOADQ (A0, A1, A2, A3, q + 2 * SLOTS);  // prefetch next-next
        CSTORE(B0, B1, B2, B3, q + SLOTS);      // compute next
        q += 2 * SLOTS;
    }

#undef LOADQ
#undef CSTORE
}

extern "C" void kernel_launch(void* const* d_in, const int* in_sizes, int n_in,
                              void* d_out, int out_size, void* d_ws, size_t ws_size,
                              hipStream_t stream) {
    const float* x  = (const float*)d_in[0];
    const float* fd = (const float*)d_in[1];
    const float* gs = (const float*)d_in[2];
    float* out = (float*)d_out;

    dim3 grid(BLKROW, NROWS);   // 2048 persistent blocks of 256 threads
    pinn_fused_conv13_v4<<<grid, 256, 0, stream>>>(x, fd, gs, out);
}